// Round 10
// baseline (2333.838 us; speedup 1.0000x reference)
//
#include <hip/hip_runtime.h>
#include <hip/hip_bf16.h>

typedef _Float16 f16;
typedef _Float16 f16x8 __attribute__((ext_vector_type(8)));
typedef float f32x4 __attribute__((ext_vector_type(4)));

#define B_ 128
#define T_ 256
#define D_ 1280
#define G3_ 3840
#define C_ 100
#define TB_ 32768  /* T_*B_ */
#define NBUF 16    /* rotating h buffers */

// ---- workspace layout (bytes) ----
#define O_H16  0ull                 // f16 [NBUF][B_][D_]  (5.25 MB, inside dead seqb region)
#define O_SEQB 0ull                 // f16 [TB_][D_]
#define O_WIH  83886080ull          // f16 [G3_][D_]
#define O_WHH  93716480ull          // f16 [G3_][D_]
#define O_XP   103546880ull         // f16 [T_][80][3][128][16] compact slabs
#define O_H32  355860480ull         // f32 [B_][D_]
#define O_BAR  356515840ull         // u32 counters: (rg*40+shard)*32 stride (128B)

// ---------------- conversion / init ----------------
__global__ void k_convert(const float* __restrict__ seq, const float* __restrict__ wih,
                          const float* __restrict__ whh, f16* __restrict__ seqb,
                          f16* __restrict__ wih16, f16* __restrict__ whh16,
                          unsigned* __restrict__ bar) {
  if (blockIdx.x == 0) {
    for (int j = threadIdx.x; j < 10240; j += 256)
      __hip_atomic_store(bar + j, 0u, __ATOMIC_RELAXED, __HIP_MEMORY_SCOPE_AGENT);
  }
  const long NSEQ = (long)TB_ * (D_ / 8);
  const long NW = (long)G3_ * (D_ / 8);
  const long total = NSEQ + 2 * NW;
  for (long i = (long)blockIdx.x * blockDim.x + threadIdx.x; i < total;
       i += (long)gridDim.x * blockDim.x) {
    const float* src;
    f16* dst;
    if (i < NSEQ) {
      long row = i / (D_ / 8), c = i % (D_ / 8);
      long t = row >> 7, b = row & 127;
      src = seq + ((b * T_ + t) * (long)D_ + c * 8);
      dst = seqb + (row * (long)D_ + c * 8);
    } else if (i < NSEQ + NW) {
      long j = i - NSEQ;
      src = wih + j * 8;
      dst = wih16 + j * 8;
    } else {
      long j = i - NSEQ - NW;
      src = whh + j * 8;
      dst = whh16 + j * 8;
    }
    float4 a = *(const float4*)src, b4 = *(const float4*)(src + 4);
    f16x8 o;
    o[0] = (f16)a.x; o[1] = (f16)a.y; o[2] = (f16)a.z; o[3] = (f16)a.w;
    o[4] = (f16)b4.x; o[5] = (f16)b4.y; o[6] = (f16)b4.z; o[7] = (f16)b4.w;
    *(f16x8*)dst = o;
  }
}

// ---------------- x_proj GEMM -> compact slab layout [t][cg][g][b][c16] ----------------
__device__ __forceinline__ void gl_lds16(const f16* g, f16* lds) {
  __builtin_amdgcn_global_load_lds((const __attribute__((address_space(1))) void*)g,
                                   (__attribute__((address_space(3))) void*)lds, 16, 0, 0);
}

__global__ __launch_bounds__(256) void k_xproj(const f16* __restrict__ A, const f16* __restrict__ Bw,
                                               const float* __restrict__ bih, f16* __restrict__ Cout) {
  __shared__ f16 Alds[128 * 32];
  __shared__ f16 Blds[128 * 32];
  int bid = blockIdx.x;
  int sb = bid / 240;
  int wi = bid % 240;
  int bm = sb * 8 + (wi & 7);
  int bn = wi >> 3;
  long brow = (long)bm * 128;
  int bcol = bn * 128;
  int tid = threadIdx.x, w = tid >> 6, l = tid & 63;
  int wm = w & 1, wn = w >> 1;

  f32x4 acc[4][4] = {};

  int sr = w * 32 + (l >> 2);
  int sc = (l & 3) * 8;
  const f16* gA = A + (brow + sr) * (long)D_ + sc;
  const f16* gB = Bw + (long)(bcol + sr) * D_ + sc;
  f16* lAw = Alds + (w * 32) * 32;
  f16* lBw = Blds + (w * 32) * 32;

  int fr = l & 15, fc = (l >> 4) * 8;

  for (int kb = 0; kb < 40; ++kb) {
    const f16* a0 = gA + kb * 32;
    const f16* b0 = gB + kb * 32;
    gl_lds16(a0, lAw);
    gl_lds16(a0 + 16 * D_, lAw + 16 * 32);
    gl_lds16(b0, lBw);
    gl_lds16(b0 + 16 * D_, lBw + 16 * 32);
    __syncthreads();
    f16x8 af[4], bf[4];
#pragma unroll
    for (int mt = 0; mt < 4; ++mt) af[mt] = *(const f16x8*)(Alds + (wm * 64 + mt * 16 + fr) * 32 + fc);
#pragma unroll
    for (int nt = 0; nt < 4; ++nt) bf[nt] = *(const f16x8*)(Blds + (wn * 64 + nt * 16 + fr) * 32 + fc);
#pragma unroll
    for (int mt = 0; mt < 4; ++mt)
#pragma unroll
      for (int nt = 0; nt < 4; ++nt)
        acc[mt][nt] = __builtin_amdgcn_mfma_f32_16x16x32_f16(af[mt], bf[nt], acc[mt][nt], 0, 0, 0);
    __syncthreads();
  }
#pragma unroll
  for (int nt = 0; nt < 4; ++nt) {
    int col = bcol + wn * 64 + nt * 16 + fr;
    int g = col / D_;
    int dcol = col - g * D_;
    int cg = dcol >> 4, c16 = dcol & 15;
    float bv = bih[col];
    f16* base = Cout + (((long)bm * 80 + cg) * 3 + g) * 2048 + c16;
#pragma unroll
    for (int mt = 0; mt < 4; ++mt) {
#pragma unroll
      for (int i = 0; i < 4; ++i) {
        int b = wm * 64 + mt * 16 + (l >> 4) * 4 + i;
        base[b * 16] = (f16)(acc[mt][nt][i] + bv);
      }
    }
  }
}

// ---------------- GRU scan: 320 blocks (4 rowgroups x 32 rows, 80 colgroups) ----------------
// KEY CHANGES vs R9:
//  (1) xproj staged into an 8-slot LDS ring via async global_load_lds, 4 steps ahead.
//      Every __syncthreads() drains vmcnt -> slot t (staged at t-4) guaranteed landed.
//      Kills the per-step synchronous HBM round-trip (the measured ~7us/step floor).
//  (2) W fragments loaded via relaxed-atomic u64 pairs (NOT rematerializable) -> truly
//      register-resident (120 VGPRs/wave, reused all 256 steps). launch_bounds(256,2).
__global__ __launch_bounds__(256, 2) void k_scan(const f16* __restrict__ whh16,
                                                 const f16* __restrict__ xproj,
                                                 const float* __restrict__ bhh,
                                                 f16* __restrict__ h16, float* __restrict__ h32,
                                                 unsigned* __restrict__ bar) {
  __shared__ float red[4][3][2][256];  // 24 KB k-partial exchange
  __shared__ f16 ring[8][3 * 512];     // 24 KB xproj ring: slot = [3 gates][32 rows][16 cols]
  int wg = blockIdx.x;
  int rg = wg & 3, cg = wg >> 2;       // 4 rowgroups (32 rows), 80 colgroups (16 cols)
  int r0 = rg * 32, d0 = cg * 16;
  int tid = threadIdx.x, w = tid >> 6, l = tid & 63;
  int fr = l & 15, fq = l >> 4;        // MFMA fragment coords
  int er = tid >> 4, ec = tid & 15;    // output element coords (rows er, er+16)
  unsigned* mycnt = bar + (rg * 40 + (cg % 40)) * 32;  // 2 blocks per shard line

  // ---- load W fragments into persistent registers via atomic loads (non-remat) ----
  const f16* wbase = whh16 + (long)(d0 + fr) * D_ + w * 320 + fq * 8;
  f16x8 wf[10][3];
#pragma unroll
  for (int j = 0; j < 10; ++j)
#pragma unroll
    for (int g = 0; g < 3; ++g) {
      union { unsigned long long u[2]; f16x8 v; } tmp;
      const unsigned long long* p =
          (const unsigned long long*)(wbase + (long)g * (D_ * D_) + j * 32);
      tmp.u[0] = __hip_atomic_load(p, __ATOMIC_RELAXED, __HIP_MEMORY_SCOPE_AGENT);
      tmp.u[1] = __hip_atomic_load(p + 1, __ATOMIC_RELAXED, __HIP_MEMORY_SCOPE_AGENT);
      wf[j][g] = tmp.v;
      asm volatile("" : "+v"(wf[j][g]));  // pin materialization point
    }

  // xproj stage: waves 0..2 copy gate w's 1KB (rows r0..r0+31) of slab (tt,cg) into ring
  auto stage = [&](int tt) {
    if (w < 3) {
      const f16* src = xproj + (((long)tt * 80 + cg) * 3) * 2048 + w * 2048 + r0 * 16 + l * 8;
      gl_lds16(src, &ring[tt & 7][w * 512]);
    }
  };

  // zero own tile of h buffer 0 (sc1 write-through, paired u32)
  if ((tid & 1) == 0) {
#pragma unroll
    for (int m = 0; m < 2; ++m) {
      unsigned* p = (unsigned*)(h16 + (r0 + m * 16 + er) * D_ + d0 + ec);
      __hip_atomic_store(p, 0u, __ATOMIC_RELAXED, __HIP_MEMORY_SCOPE_AGENT);
    }
  }

  float bh0 = bhh[0 * D_ + d0 + ec];
  float bh1 = bhh[1 * D_ + d0 + ec];
  float bh2 = bhh[2 * D_ + d0 + ec];
  float hreg[2] = {0.f, 0.f};

  auto poll = [&](unsigned target) {
    unsigned it = 0;
    for (;;) {
      unsigned v = target;
      if (l < 40)
        v = __hip_atomic_load(bar + (rg * 40 + l) * 32, __ATOMIC_RELAXED, __HIP_MEMORY_SCOPE_AGENT);
      if (__all(v >= target)) break;
      __builtin_amdgcn_s_sleep(1);
      if (++it > 500000u) {  // paranoia: RMW reads the coherent point
        if (l < 40)
          v = __hip_atomic_fetch_add(bar + (rg * 40 + l) * 32, 0u, __ATOMIC_RELAXED,
                                     __HIP_MEMORY_SCOPE_AGENT);
        if (__all(v >= target)) break;
        it = 0;
      }
    }
  };

  // prologue: stage slots for t=0..3
  stage(0); stage(1); stage(2); stage(3);

  // initial barrier + cross-replay cache scrub (syncthreads drains the stages too)
  __syncthreads();
  if (tid == 0)
    __hip_atomic_fetch_add(mycnt, 1u, __ATOMIC_RELAXED, __HIP_MEMORY_SCOPE_AGENT);
  if (tid < 64) {
    poll(2u);
    if (tid == 0) __builtin_amdgcn_fence(__ATOMIC_ACQUIRE, "agent");
  }
  __syncthreads();

  unsigned tgt = 4u;
  for (int t = 0; t < T_; ++t) {
    if (t + 4 < T_) stage(t + 4);  // async; lands by this step's end-of-step syncthreads
    const f16* hc = h16 + (long)(t & (NBUF - 1)) * (B_ * D_);
    const f16* ar0 = hc + (long)(r0 + fr) * D_ + w * 320 + fq * 8;
    f32x4 acc[2][3] = {};
#pragma unroll
    for (int j = 0; j < 10; ++j) {
      f16x8 a0 = *(const f16x8*)(ar0 + j * 32);           // rows r0..r0+15
      f16x8 a1 = *(const f16x8*)(ar0 + 16 * D_ + j * 32); // rows r0+16..r0+31
      acc[0][0] = __builtin_amdgcn_mfma_f32_16x16x32_f16(a0, wf[j][0], acc[0][0], 0, 0, 0);
      acc[0][1] = __builtin_amdgcn_mfma_f32_16x16x32_f16(a0, wf[j][1], acc[0][1], 0, 0, 0);
      acc[0][2] = __builtin_amdgcn_mfma_f32_16x16x32_f16(a0, wf[j][2], acc[0][2], 0, 0, 0);
      acc[1][0] = __builtin_amdgcn_mfma_f32_16x16x32_f16(a1, wf[j][0], acc[1][0], 0, 0, 0);
      acc[1][1] = __builtin_amdgcn_mfma_f32_16x16x32_f16(a1, wf[j][1], acc[1][1], 0, 0, 0);
      acc[1][2] = __builtin_amdgcn_mfma_f32_16x16x32_f16(a1, wf[j][2], acc[1][2], 0, 0, 0);
    }
    // k-reduce via LDS
#pragma unroll
    for (int m = 0; m < 2; ++m)
#pragma unroll
      for (int g = 0; g < 3; ++g)
#pragma unroll
        for (int i = 0; i < 4; ++i)
          red[w][g][m][(((fq * 4 + i) * 16) + fr) ^ (fq << 2)] = acc[m][g][i];
    __syncthreads();
    int pr = tid ^ ((tid >> 6) << 2);
    const f16* xs = ring[t & 7];
    float hnew[2];
#pragma unroll
    for (int m = 0; m < 2; ++m) {
      float s0 = red[0][0][m][pr] + red[1][0][m][pr] + red[2][0][m][pr] + red[3][0][m][pr];
      float s1 = red[0][1][m][pr] + red[1][1][m][pr] + red[2][1][m][pr] + red[3][1][m][pr];
      float s2 = red[0][2][m][pr] + red[1][2][m][pr] + red[2][2][m][pr] + red[3][2][m][pr];
      int xo = (m * 16 + er) * 16 + ec;
      float r = 1.f / (1.f + __expf(-((float)xs[xo] + s0 + bh0)));
      float z = 1.f / (1.f + __expf(-((float)xs[512 + xo] + s1 + bh1)));
      float pn = (float)xs[1024 + xo] + r * (s2 + bh2);
      pn = fminf(fmaxf(pn, -30.f), 30.f);
      float e2 = __expf(-2.f * pn);
      float nn = (1.f - e2) / (1.f + e2);
      hnew[m] = (1.f - z) * nn + z * hreg[m];
      hreg[m] = hnew[m];
    }
    if (t == T_ - 1) break;
    // store h_{t+1}: paired-u32 sc1 write-through
    f16* hn = h16 + (long)((t + 1) & (NBUF - 1)) * (B_ * D_);
#pragma unroll
    for (int m = 0; m < 2; ++m) {
      unsigned short bits = __builtin_bit_cast(unsigned short, (f16)hnew[m]);
      unsigned other = (unsigned)__shfl_xor((int)bits, 1);
      if ((tid & 1) == 0) {
        unsigned val = (unsigned)bits | (other << 16);
        __hip_atomic_store((unsigned*)(hn + (r0 + m * 16 + er) * D_ + d0 + ec), val,
                           __ATOMIC_RELAXED, __HIP_MEMORY_SCOPE_AGENT);
      }
    }
    __syncthreads();  // drains sc1 stores + pending stages; closes red[]/ring WAR windows
    if (tid == 0)
      __hip_atomic_fetch_add(mycnt, 1u, __ATOMIC_RELAXED, __HIP_MEMORY_SCOPE_AGENT);
    if (tid < 64) {
      poll(tgt);
      if (tid == 0 && (((t + 1) & (NBUF - 1)) == 0))
        __builtin_amdgcn_fence(__ATOMIC_ACQUIRE, "agent");  // periodic stale-line scrub
    }
    __syncthreads();
    tgt += 2u;
  }
  // final h in fp32 for the scores kernel
#pragma unroll
  for (int m = 0; m < 2; ++m) h32[(r0 + m * 16 + er) * D_ + d0 + ec] = hreg[m];
}

// ---------------- scores: out[b][c] = sum_d h[b][d]*cand[b][c][d] (fp32) ----------------
__global__ __launch_bounds__(256) void k_scores(const float* __restrict__ h32,
                                                const float* __restrict__ cand,
                                                float* __restrict__ out) {
  int gw = blockIdx.x * 4 + (threadIdx.x >> 6);
  int l = threadIdx.x & 63;
  int b = gw / C_, c = gw % C_;
  const float* hp = h32 + (long)b * D_;
  const float* cp = cand + ((long)b * C_ + c) * D_;
  float s = 0.f;
#pragma unroll
  for (int q = 0; q < 5; ++q) {
    int d = q * 256 + l * 4;
    float4 hv = *(const float4*)(hp + d);
    float4 cv = *(const float4*)(cp + d);
    s += hv.x * cv.x + hv.y * cv.y + hv.z * cv.z + hv.w * cv.w;
  }
#pragma unroll
  for (int off = 32; off > 0; off >>= 1) s += __shfl_down(s, off);
  if (l == 0) out[(long)b * C_ + c] = s;
}

extern "C" void kernel_launch(void* const* d_in, const int* in_sizes, int n_in, void* d_out,
                              int out_size, void* d_ws, size_t ws_size, hipStream_t stream) {
  const float* seq = (const float*)d_in[0];
  const float* cand = (const float*)d_in[1];
  const float* wih = (const float*)d_in[2];
  const float* whh = (const float*)d_in[3];
  const float* bih = (const float*)d_in[4];
  const float* bhh = (const float*)d_in[5];
  char* ws = (char*)d_ws;
  f16* seqb = (f16*)(ws + O_SEQB);
  f16* wih16 = (f16*)(ws + O_WIH);
  f16* whh16 = (f16*)(ws + O_WHH);
  f16* xp = (f16*)(ws + O_XP);
  f16* h16 = (f16*)(ws + O_H16);  // rotating buffers, overlapping seqb (dead by then)
  float* h32 = (float*)(ws + O_H32);
  unsigned* bar = (unsigned*)(ws + O_BAR);

  k_convert<<<2048, 256, 0, stream>>>(seq, wih, whh, seqb, wih16, whh16, bar);
  k_xproj<<<7680, 256, 0, stream>>>(seqb, wih16, bih, xp);
  k_scan<<<320, 256, 0, stream>>>(whh16, xp, bhh, h16, h32, bar);
  k_scores<<<3200, 256, 0, stream>>>(h32, cand, (float*)d_out);
}